// Round 15
// baseline (385.876 us; speedup 1.0000x reference)
//
#include <hip/hip_runtime.h>
#include <hip/hip_bf16.h>

#define NB 32768
#define NSLOT 64
#define EPS 1e-5f

using bf16 = __hip_bfloat16;
using u32  = unsigned int;
typedef _Float16 h2 __attribute__((ext_vector_type(2)));

// ---------- storage-type helpers (f32 or bf16 workspace) ----------
template<typename TY> __device__ __forceinline__ float ldF(const TY* p, size_t i);
template<> __device__ __forceinline__ float ldF<float>(const float* p, size_t i){ return p[i]; }
template<> __device__ __forceinline__ float ldF<bf16 >(const bf16*  p, size_t i){ return __bfloat162float(p[i]); }
template<typename TY> __device__ __forceinline__ void stF(TY* p, size_t i, float v);
template<> __device__ __forceinline__ void stF<float>(float* p, size_t i, float v){ p[i] = v; }
template<> __device__ __forceinline__ void stF<bf16 >(bf16*  p, size_t i, float v){ p[i] = __float2bfloat16(v); }

// f16 pair dot with f32 accumulate
__device__ __forceinline__ float DOT2(u32 a, u32 b, float c){
#if __has_builtin(__builtin_amdgcn_fdot2)
    union { u32 u; h2 h; } ua, ub; ua.u = a; ub.u = b;
    return __builtin_amdgcn_fdot2(ua.h, ub.h, c, false);
#else
    union { u32 u; _Float16 h[2]; } ua, ub; ua.u = a; ub.u = b;
    return c + (float)ua.h[0]*(float)ub.h[0] + (float)ua.h[1]*(float)ub.h[1];
#endif
}
__device__ __forceinline__ float dot8(uint4 e, uint4 w, float acc){
    acc = DOT2(e.x, w.x, acc); acc = DOT2(e.y, w.y, acc);
    acc = DOT2(e.z, w.z, acc); acc = DOT2(e.w, w.w, acc);
    return acc;
}

// y workspace layout (per tau, per sample): slot = k*64 + tg*16 + o, t = 4*k + tg.
// Lane l = tg*16+o stores slot k*64+l -> contiguous wave stores.

// wlU word offsets (f16 packed, rows padded to 16 halves with ZEROS).
#define W1W 0       // t1w1T [16 o][6 kh][8dw], o-stride 52dw
#define W2W 832     // t2w1T [16 o][3 j ][8dw], o-stride 28dw
#define W3W 1280    // c1w1T [16 o][5 kh][8dw], o-stride 44dw
#define C0W 1984    // c0wT  [9 d][8dw]
#define WLW 2056

// ---------------- Kernel A: MLP + xcorr + first convs + BN1 stats ----------------
// r12 structure; t2 FUSED into t1's even-kh iterations (t2's data rows are a subset
// of t1's) with unroll 2 — r9's spill came from full unroll, not the fusion.
template<typename TY>
__global__ __launch_bounds__(512)
void kA(const float* __restrict__ raw, const float* __restrict__ eegf,
        const float* __restrict__ fgw1, const float* __restrict__ fgb1,
        const float* __restrict__ fgw2, const float* __restrict__ fgb2,
        const float* __restrict__ t1w1, const float* __restrict__ t1b1,
        const float* __restrict__ t2w1, const float* __restrict__ t2b1,
        const float* __restrict__ c0w,  const float* __restrict__ c0b,
        const float* __restrict__ c1w1, const float* __restrict__ c1b1,
        TY* __restrict__ yws, float* __restrict__ stat1)
{
    __shared__ __align__(16) u32 rawU[8][396];   // f16 [12 c][66 h] (63 used, pad=0)
    __shared__ __align__(16) u32 eTH[8][456];    // f16 [57 t][16 h]: eeg c0..11, later ec d0..8
    __shared__ __align__(16) u32 wlU[WLW];
    __shared__ float bF[64];                     // B1 0-15, B2 16-31, B3 32-47, C0B 48-56
    __shared__ float h35_s[8][36];
    __shared__ float filt_s[8][8];
    __shared__ u32   filtH[8][4];
    __shared__ float stat_s[96];

    const int tid = threadIdx.x;
    const int l   = tid & 63;
    const int s   = tid >> 6;
    const int gs  = blockIdx.x * 8 + s;

    if (tid < 96) stat_s[tid] = 0.f;
    {
        _Float16* hp = (_Float16*)wlU;
        for (int idx = tid; idx < 1536; idx += 512) {
            int o = idx / 96, r = idx % 96, kh = r >> 4, h = r & 15;
            hp[o * 104 + kh * 16 + h] = (_Float16)((h < 12) ? t1w1[o * 72 + h * 6 + kh] : 0.f);
        }
        for (int idx = tid; idx < 768; idx += 512) {
            int o = idx / 48, r = idx % 48, j = r >> 4, h = r & 15;
            hp[2 * W2W + o * 56 + j * 16 + h] = (_Float16)((h < 12) ? t2w1[o * 36 + h * 3 + j] : 0.f);
        }
        for (int idx = tid; idx < 1280; idx += 512) {
            int o = idx / 80, r = idx % 80, kh = r >> 4, h = r & 15;
            hp[2 * W3W + o * 88 + kh * 16 + h] = (_Float16)((h < 9) ? c1w1[o * 45 + kh * 9 + h] : 0.f);
        }
        for (int idx = tid; idx < 144; idx += 512) {
            int d = idx / 16, h = idx & 15;
            hp[2 * C0W + d * 16 + h] = (_Float16)((h < 12) ? c0w[h * 9 + d] : 0.f);
        }
        if (tid < 16) { bF[tid] = t1b1[tid]; bF[16 + tid] = t2b1[tid]; bF[32 + tid] = c1b1[tid]; }
        if (tid < 9)  bF[48 + tid] = c0b[tid];
    }
    {
        _Float16* rH = (_Float16*)rawU[s];
        for (int r = l; r < 792; r += 64) {
            int c = r / 66, i = r - c * 66;
            rH[r] = (_Float16)((i < 63) ? raw[(size_t)gs * 756 + c * 63 + i] : 0.f);
        }
    }
    __syncthreads();

    if (l < 35) {
        const float* e = eegf + (size_t)gs * 168;
        float a0 = 0.f, a1 = 0.f, a2 = 0.f, a3 = 0.f;
        #pragma unroll 2
        for (int i = 0; i < 168; i += 4) {
            a0 = fmaf(e[i],     fgw1[i * 35 + l],       a0);
            a1 = fmaf(e[i + 1], fgw1[(i + 1) * 35 + l], a1);
            a2 = fmaf(e[i + 2], fgw1[(i + 2) * 35 + l], a2);
            a3 = fmaf(e[i + 3], fgw1[(i + 3) * 35 + l], a3);
        }
        h35_s[s][l] = tanhf(a0 + a1 + a2 + a3 + fgb1[l]);
    }
    if (l < 7) {
        float a = fgb2[l];
        for (int j = 0; j < 35; ++j) a = fmaf(h35_s[s][j], fgw2[j * 7 + l], a);
        filt_s[s][l] = tanhf(a);
    }
    if (l == 7) filt_s[s][7] = 0.f;
    if (l < 4) {
        union { u32 u; _Float16 h[2]; } pk;
        pk.h[0] = (_Float16)filt_s[s][2 * l];
        pk.h[1] = (_Float16)filt_s[s][2 * l + 1];
        filtH[s][l] = pk.u;
    }

    const int o = l & 15, tg = l >> 4;      // t = tg + 4k; k=4 valid only for tg<2
    const bool k4 = (tg < 2);

    {
        const u32 fp0 = filtH[s][0], fp1 = filtH[s][1], fp2 = filtH[s][2], fp3 = filtH[s][3];
        const int cc = l & 15;
        const u32* rw = rawU[s] + (cc < 12 ? cc : 0) * 33;
        const u32 sh = (u32)(tg & 1) * 16;
        _Float16* eH = (_Float16*)eTH[s];
        #pragma unroll 3
        for (int j = 0; j < 15; ++j) {
            int t = tg + 4 * j;
            if (t < 57) {
                const u32* p = rw + (t >> 1);
                u32 w0 = p[0], w1 = p[1], w2 = p[2], w3 = p[3], w4 = p[4];
                u32 u0 = __builtin_amdgcn_alignbit(w1, w0, sh);
                u32 u1 = __builtin_amdgcn_alignbit(w2, w1, sh);
                u32 u2 = __builtin_amdgcn_alignbit(w3, w2, sh);
                u32 u3 = __builtin_amdgcn_alignbit(w4, w3, sh);
                float v = DOT2(u3, fp3, 0.f);
                v = DOT2(u2, fp2, v); v = DOT2(u1, fp1, v); v = DOT2(u0, fp0, v);
                if (cc >= 12) v = 0.f;
                eH[t * 16 + cc] = (_Float16)v;
            }
        }
    }

    // ---- tau=0 + tau=1 FUSED: t2 accumulates on t1's even-kh data reads ----
    {
        const float b1v = bF[o], b2v = bF[16 + o];
        float a0 = b1v, a1 = b1v, a2 = b1v, a3 = b1v, a4 = b1v;
        float g0 = b2v, g1 = b2v, g2 = b2v, g3 = b2v, g4 = b2v;
        const u32* w1b = wlU + W1W + o * 52;
        const u32* w2b = wlU + W2W + o * 28;
        const u32* eU  = eTH[s];
        #pragma unroll 2
        for (int kh = 0; kh < 6; ++kh) {
            const uint4 wa = *(const uint4*)(w1b + kh * 8);
            const uint4 wb = *(const uint4*)(w1b + kh * 8 + 4);
            const bool ev = (kh & 1) == 0;
            uint4 va, vb;
            if (ev) { va = *(const uint4*)(w2b + (kh >> 1) * 8); vb = *(const uint4*)(w2b + (kh >> 1) * 8 + 4); }
            const u32* r = eU + (3 * tg + kh) * 8;
            uint4 ea, eb;
            ea = *(const uint4*)(r);       eb = *(const uint4*)(r + 4);
            a0 = dot8(eb, wb, dot8(ea, wa, a0));
            if (ev) g0 = dot8(eb, vb, dot8(ea, va, g0));
            ea = *(const uint4*)(r + 96);  eb = *(const uint4*)(r + 100);
            a1 = dot8(eb, wb, dot8(ea, wa, a1));
            if (ev) g1 = dot8(eb, vb, dot8(ea, va, g1));
            ea = *(const uint4*)(r + 192); eb = *(const uint4*)(r + 196);
            a2 = dot8(eb, wb, dot8(ea, wa, a2));
            if (ev) g2 = dot8(eb, vb, dot8(ea, va, g2));
            ea = *(const uint4*)(r + 288); eb = *(const uint4*)(r + 292);
            a3 = dot8(eb, wb, dot8(ea, wa, a3));
            if (ev) g3 = dot8(eb, vb, dot8(ea, va, g3));
            if (k4) {
                ea = *(const uint4*)(r + 384); eb = *(const uint4*)(r + 388);
                a4 = dot8(eb, wb, dot8(ea, wa, a4));
                if (ev) g4 = dot8(eb, vb, dot8(ea, va, g4));
            }
        }
        // stores + stats, tau=0
        size_t base = (size_t)gs * 288 + l;
        stF<TY>(yws, base,       a0); stF<TY>(yws, base + 64,  a1);
        stF<TY>(yws, base + 128, a2); stF<TY>(yws, base + 192, a3);
        float sum = a0 + a1 + a2 + a3;
        float sq  = fmaf(a0, a0, fmaf(a1, a1, fmaf(a2, a2, a3 * a3)));
        if (k4) { stF<TY>(yws, base + 256, a4); sum += a4; sq = fmaf(a4, a4, sq); }
        sum += __shfl_xor(sum, 16); sq += __shfl_xor(sq, 16);
        sum += __shfl_xor(sum, 32); sq += __shfl_xor(sq, 32);
        if (tg == 0) { atomicAdd(&stat_s[o * 2], sum); atomicAdd(&stat_s[o * 2 + 1], sq); }
        // stores + stats, tau=1
        base = (size_t)NB * 288 + (size_t)gs * 288 + l;
        stF<TY>(yws, base,       g0); stF<TY>(yws, base + 64,  g1);
        stF<TY>(yws, base + 128, g2); stF<TY>(yws, base + 192, g3);
        sum = g0 + g1 + g2 + g3;
        sq  = fmaf(g0, g0, fmaf(g1, g1, fmaf(g2, g2, g3 * g3)));
        if (k4) { stF<TY>(yws, base + 256, g4); sum += g4; sq = fmaf(g4, g4, sq); }
        sum += __shfl_xor(sum, 16); sq += __shfl_xor(sq, 16);
        sum += __shfl_xor(sum, 32); sq += __shfl_xor(sq, 32);
        if (tg == 0) { atomicAdd(&stat_s[32 + o * 2], sum); atomicAdd(&stat_s[32 + o * 2 + 1], sq); }
    }

    if (l < 63) {
        const int dd = l % 9, tc = l / 9;
        const u32* cw = wlU + C0W + dd * 8;
        const uint4 wca = *(const uint4*)(cw);
        const uint2 wcb = *(const uint2*)(cw + 4);
        const float cb  = bF[48 + dd];
        _Float16* eH = (_Float16*)eTH[s];
        const u32* eU = eTH[s];
        #pragma unroll 3
        for (int j = 0; j < 9; ++j) {
            int t = tc + 7 * j;
            if (t < 57) {
                const u32* r = eU + t * 8;
                uint4 ea = *(const uint4*)r;
                uint2 eb = *(const uint2*)(r + 4);
                float a = dot8(ea, wca, cb);
                a = DOT2(eb.x, wcb.x, a); a = DOT2(eb.y, wcb.y, a);
                eH[t * 16 + dd] = (_Float16)fmaxf(a, 0.f);
            }
        }
    }
    {
        _Float16* eH = (_Float16*)eTH[s];
        for (int m = l; m < 171; m += 64) { int t = m / 3, dd2 = 9 + m % 3; eH[t * 16 + dd2] = (_Float16)0.f; }
    }

    {
        const float b3v = bF[32 + o];
        float a0 = b3v, a1 = b3v, a2 = b3v, a3 = b3v, a4 = b3v;
        const u32* w3b = wlU + W3W + o * 44;
        const u32* eU  = eTH[s];
        #pragma unroll 2
        for (int kh = 0; kh < 5; ++kh) {
            const uint4 wa = *(const uint4*)(w3b + kh * 8);
            const uint2 wb = *(const uint2*)(w3b + kh * 8 + 4);
            const u32* r = eU + (3 * tg + kh) * 8;
            uint4 ea; uint2 eb;
            ea = *(const uint4*)(r);       eb = *(const uint2*)(r + 4);
            a0 = dot8(ea, wa, a0); a0 = DOT2(eb.x, wb.x, a0); a0 = DOT2(eb.y, wb.y, a0);
            ea = *(const uint4*)(r + 96);  eb = *(const uint2*)(r + 100);
            a1 = dot8(ea, wa, a1); a1 = DOT2(eb.x, wb.x, a1); a1 = DOT2(eb.y, wb.y, a1);
            ea = *(const uint4*)(r + 192); eb = *(const uint2*)(r + 196);
            a2 = dot8(ea, wa, a2); a2 = DOT2(eb.x, wb.x, a2); a2 = DOT2(eb.y, wb.y, a2);
            ea = *(const uint4*)(r + 288); eb = *(const uint2*)(r + 292);
            a3 = dot8(ea, wa, a3); a3 = DOT2(eb.x, wb.x, a3); a3 = DOT2(eb.y, wb.y, a3);
            if (k4) {
                ea = *(const uint4*)(r + 384); eb = *(const uint2*)(r + 388);
                a4 = dot8(ea, wa, a4); a4 = DOT2(eb.x, wb.x, a4); a4 = DOT2(eb.y, wb.y, a4);
            }
        }
        size_t base = (size_t)2 * NB * 288 + (size_t)gs * 288 + l;
        stF<TY>(yws, base,       a0); stF<TY>(yws, base + 64,  a1);
        stF<TY>(yws, base + 128, a2); stF<TY>(yws, base + 192, a3);
        float sum = a0 + a1 + a2 + a3;
        float sq  = fmaf(a0, a0, fmaf(a1, a1, fmaf(a2, a2, a3 * a3)));
        if (k4) { stF<TY>(yws, base + 256, a4); sum += a4; sq = fmaf(a4, a4, sq); }
        sum += __shfl_xor(sum, 16); sq += __shfl_xor(sq, 16);
        sum += __shfl_xor(sum, 32); sq += __shfl_xor(sq, 32);
        if (tg == 0) { atomicAdd(&stat_s[64 + o * 2], sum); atomicAdd(&stat_s[64 + o * 2 + 1], sq); }
    }
    __syncthreads();
    if (tid < 96) atomicAdd(&stat1[(blockIdx.x & (NSLOT - 1)) * 96 + tid], stat_s[tid]);
}

// ---------------- BN finalize (stage 1 or 2) ----------------
__global__ void kBN(const float* __restrict__ statp,
                    const float* __restrict__ g0, const float* __restrict__ be0,
                    const float* __restrict__ g1, const float* __restrict__ be1,
                    const float* __restrict__ g2, const float* __restrict__ be2,
                    float nInv, float* __restrict__ bnp)
{
    int tid = threadIdx.x;
    if (tid >= 48) return;
    int tau = tid / 16, o = tid % 16;
    float sum = 0.f, sq = 0.f;
    for (int sl = 0; sl < NSLOT; ++sl) {
        sum += statp[sl * 96 + tid * 2];
        sq  += statp[sl * 96 + tid * 2 + 1];
    }
    float mean = sum * nInv;
    float var  = sq * nInv - mean * mean;
    const float* g  = (tau == 0) ? g0 : (tau == 1) ? g1 : g2;
    const float* be = (tau == 0) ? be0 : (tau == 1) ? be1 : be2;
    float scale = g[o] / sqrtf(var + EPS);
    float shift = be[o] - mean * scale;
    bnp[tid * 2]     = scale;
    bnp[tid * 2 + 1] = shift;
}

// ---------------- Kernel C: BN1+relu, second convs (f16/dot2), BN2 stats ----------------
#define C_W1 0      // [16 o][6 kh][8dw], o-stride 52
#define C_W2 832    // [16 o][3 j ][8dw], o-stride 28
#define C_W3 1280   // [16 o][5 kh][8dw], o-stride 44
#define C_WL 1984

template<typename TY>
__global__ __launch_bounds__(512)
void kC(const TY* __restrict__ yws, const float* __restrict__ bn1,
        const float* __restrict__ t1w2, const float* __restrict__ t1b2,
        const float* __restrict__ t2w2, const float* __restrict__ t2b2,
        const float* __restrict__ c1w2, const float* __restrict__ c1b2,
        TY* __restrict__ zws, float* __restrict__ stat2)
{
    __shared__ __align__(16) u32 hT[3][8][144];   // f16 [18 t][8 dw] per tau,sample
    __shared__ __align__(16) u32 wl2[C_WL];
    __shared__ float bB[48];
    __shared__ float bnp[96];
    __shared__ float stat_s[96];

    const int tid = threadIdx.x;
    const int l   = tid & 63;
    const int s   = tid >> 6;
    const int gs  = blockIdx.x * 8 + s;

    if (tid < 96) { stat_s[tid] = 0.f; bnp[tid] = bn1[tid]; }
    {
        _Float16* hp = (_Float16*)wl2;
        for (int idx = tid; idx < 1536; idx += 512) { int o = idx / 96, r = idx % 96, kh = r >> 4, c = r & 15;
            hp[o * 104 + kh * 16 + c] = (_Float16)t1w2[o * 96 + c * 6 + kh]; }
        for (int idx = tid; idx < 768; idx += 512) { int o = idx / 48, r = idx % 48, j = r >> 4, c = r & 15;
            hp[2 * C_W2 + o * 56 + j * 16 + c] = (_Float16)t2w2[o * 48 + c * 3 + j]; }
        for (int idx = tid; idx < 1280; idx += 512) { int o = idx / 80, r = idx % 80, kh = r >> 4, c = r & 15;
            hp[2 * C_W3 + o * 88 + kh * 16 + c] = (_Float16)c1w2[o * 80 + c * 5 + kh]; }
        if (tid < 16) { bB[tid] = t1b2[tid]; bB[16 + tid] = t2b2[tid]; bB[32 + tid] = c1b2[tid]; }
    }
    __syncthreads();

    const int o = l & 15, tg = l >> 4;
    const bool k4 = (tg == 0);

    #pragma unroll
    for (int tau = 0; tau < 3; ++tau) {
        const float sc = bnp[(tau * 16 + o) * 2], sh = bnp[(tau * 16 + o) * 2 + 1];
        _Float16* hH = (_Float16*)hT[tau][s];
        const size_t yb = (size_t)tau * NB * 288 + (size_t)gs * 288 + l;
        #pragma unroll
        for (int k = 0; k < 4; ++k) {
            float v = ldF<TY>(yws, yb + k * 64);
            hH[(4 * k + tg) * 16 + o] = (_Float16)fmaxf(fmaf(v, sc, sh), 0.f);
        }
        if (l < 32) {
            float v = ldF<TY>(yws, yb + 256);
            hH[(16 + tg) * 16 + o] = (_Float16)fmaxf(fmaf(v, sc, sh), 0.f);
        }
    }

    {
        const float b = bB[o];
        float a0 = b, a1 = b;
        const u32* w = wl2 + C_W1 + o * 52;
        const u32* h0 = hT[0][s];
        #pragma unroll 2
        for (int kh = 0; kh < 6; ++kh) {
            const uint4 wa = *(const uint4*)(w + kh * 8);
            const uint4 wb = *(const uint4*)(w + kh * 8 + 4);
            const u32* r = h0 + (3 * tg + kh) * 8;
            uint4 ea = *(const uint4*)r, eb = *(const uint4*)(r + 4);
            a0 = dot8(eb, wb, dot8(ea, wa, a0));
            if (k4) {
                const u32* r2 = h0 + (12 + kh) * 8;
                uint4 fa = *(const uint4*)r2, fb = *(const uint4*)(r2 + 4);
                a1 = dot8(fb, wb, dot8(fa, wa, a1));
            }
        }
        size_t zb = (size_t)gs * 80;
        stF<TY>(zws, zb + o * 5 + tg, a0);
        float sum = a0, sq = a0 * a0;
        if (k4) { stF<TY>(zws, zb + o * 5 + 4, a1); sum += a1; sq = fmaf(a1, a1, sq); }
        sum += __shfl_xor(sum, 16); sq += __shfl_xor(sq, 16);
        sum += __shfl_xor(sum, 32); sq += __shfl_xor(sq, 32);
        if (tg == 0) { atomicAdd(&stat_s[o * 2], sum); atomicAdd(&stat_s[o * 2 + 1], sq); }
    }

    {
        const float b = bB[16 + o];
        float a0 = b, a1 = b;
        const u32* w = wl2 + C_W2 + o * 28;
        const u32* h1 = hT[1][s];
        #pragma unroll
        for (int j = 0; j < 3; ++j) {
            const uint4 wa = *(const uint4*)(w + j * 8);
            const uint4 wb = *(const uint4*)(w + j * 8 + 4);
            const u32* r = h1 + (3 * tg + 2 * j) * 8;
            uint4 ea = *(const uint4*)r, eb = *(const uint4*)(r + 4);
            a0 = dot8(eb, wb, dot8(ea, wa, a0));
            if (k4) {
                const u32* r2 = h1 + (12 + 2 * j) * 8;
                uint4 fa = *(const uint4*)r2, fb = *(const uint4*)(r2 + 4);
                a1 = dot8(fb, wb, dot8(fa, wa, a1));
            }
        }
        size_t zb = (size_t)NB * 80 + (size_t)gs * 80;
        stF<TY>(zws, zb + o * 5 + tg, a0);
        float sum = a0, sq = a0 * a0;
        if (k4) { stF<TY>(zws, zb + o * 5 + 4, a1); sum += a1; sq = fmaf(a1, a1, sq); }
        sum += __shfl_xor(sum, 16); sq += __shfl_xor(sq, 16);
        sum += __shfl_xor(sum, 32); sq += __shfl_xor(sq, 32);
        if (tg == 0) { atomicAdd(&stat_s[32 + o * 2], sum); atomicAdd(&stat_s[32 + o * 2 + 1], sq); }
    }

    {
        const float b = bB[32 + o];
        float a0 = b, a1 = b;
        const u32* w = wl2 + C_W3 + o * 44;
        const u32* h2 = hT[2][s];
        #pragma unroll 2
        for (int kh = 0; kh < 5; ++kh) {
            const uint4 wa = *(const uint4*)(w + kh * 8);
            const uint4 wb = *(const uint4*)(w + kh * 8 + 4);
            const u32* r = h2 + (3 * tg + kh) * 8;
            uint4 ea = *(const uint4*)r, eb = *(const uint4*)(r + 4);
            a0 = dot8(eb, wb, dot8(ea, wa, a0));
            if (k4) {
                const u32* r2 = h2 + (12 + kh) * 8;
                uint4 fa = *(const uint4*)r2, fb = *(const uint4*)(r2 + 4);
                a1 = dot8(fb, wb, dot8(fa, wa, a1));
            }
        }
        size_t zb = (size_t)2 * NB * 80 + (size_t)gs * 80;
        stF<TY>(zws, zb + o * 5 + tg, a0);
        float sum = a0, sq = a0 * a0;
        if (k4) { stF<TY>(zws, zb + o * 5 + 4, a1); sum += a1; sq = fmaf(a1, a1, sq); }
        sum += __shfl_xor(sum, 16); sq += __shfl_xor(sq, 16);
        sum += __shfl_xor(sum, 32); sq += __shfl_xor(sq, 32);
        if (tg == 0) { atomicAdd(&stat_s[64 + o * 2], sum); atomicAdd(&stat_s[64 + o * 2 + 1], sq); }
    }
    __syncthreads();
    if (tid < 96) atomicAdd(&stat2[(blockIdx.x & (NSLOT - 1)) * 96 + tid], stat_s[tid]);
}

// ---------------- Kernel E: BN2+relu, feats, FC (f16 dot2), tanh ----------------
template<typename TY>
__global__ __launch_bounds__(256)
void kE(const TY* __restrict__ zws, const float* __restrict__ bn2,
        const float* __restrict__ fcw, const float* __restrict__ fcb,
        float* __restrict__ out)
{
    __shared__ __align__(16) u32 fcwH[8000];
    __shared__ __align__(16) u32 featsH[8][160];
    __shared__ float fcb_s[50];
    __shared__ float bnp[96];
    const int tid = threadIdx.x;
    const int s0  = blockIdx.x * 8;

    if (tid < 96) bnp[tid] = bn2[tid];
    if (tid < 50) fcb_s[tid] = fcb[tid];
    for (int idx = tid; idx < 8000; idx += 256) {
        int fp = idx / 50, u = idx % 50;
        union { u32 v; _Float16 h[2]; } pk;
        pk.h[0] = (_Float16)fcw[(2 * fp) * 50 + u];
        pk.h[1] = (_Float16)fcw[(2 * fp + 1) * 50 + u];
        fcwH[idx] = pk.v;
    }
    __syncthreads();

    for (int idx = tid; idx < 2560; idx += 256) {
        int s = idx / 320, f = idx % 320;
        int g = f / 80; int tau = (g == 3) ? 2 : g;
        int r = f % 80, o = r / 5;
        float v = ldF<TY>(zws, (size_t)tau * NB * 80 + (size_t)(s0 + s) * 80 + r);
        float x = fmaxf(fmaf(v, bnp[(tau * 16 + o) * 2], bnp[(tau * 16 + o) * 2 + 1]), 0.f);
        ((_Float16*)featsH[s])[f] = (_Float16)x;
    }
    __syncthreads();

    const int sA = tid / 50, uA = tid % 50;
    const int iB = tid + 256, sB = iB / 50, uB = iB % 50;
    float accA = fcb_s[uA];
    float accB = (tid < 144) ? fcb_s[uB] : 0.f;
    #pragma unroll 4
    for (int fp = 0; fp < 160; ++fp) {
        u32 w1 = fcwH[fp * 50 + uA];
        u32 x1 = featsH[sA][fp];
        accA = DOT2(x1, w1, accA);
        if (tid < 144) {
            u32 w2 = fcwH[fp * 50 + uB];
            u32 x2 = featsH[sB][fp];
            accB = DOT2(x2, w2, accB);
        }
    }
    out[(size_t)(s0 + sA) * 50 + uA] = tanhf(accA);
    if (tid < 144) out[(size_t)(s0 + sB) * 50 + uB] = tanhf(accB);
}

// ---------------- host launcher ----------------
template<typename TY>
static void launch_all(void* const* d_in, void* d_out, void* d_ws, hipStream_t stream)
{
    const float* raw  = (const float*)d_in[0];
    const float* eegf = (const float*)d_in[1];
    const float* fgw1 = (const float*)d_in[2];
    const float* fgb1 = (const float*)d_in[3];
    const float* fgw2 = (const float*)d_in[4];
    const float* fgb2 = (const float*)d_in[5];
    const float* t1w1 = (const float*)d_in[6];
    const float* t1b1 = (const float*)d_in[7];
    const float* t1g1 = (const float*)d_in[8];
    const float* t1be1= (const float*)d_in[9];
    const float* t1w2 = (const float*)d_in[10];
    const float* t1b2 = (const float*)d_in[11];
    const float* t1g2 = (const float*)d_in[12];
    const float* t1be2= (const float*)d_in[13];
    const float* t2w1 = (const float*)d_in[14];
    const float* t2b1 = (const float*)d_in[15];
    const float* t2g1 = (const float*)d_in[16];
    const float* t2be1= (const float*)d_in[17];
    const float* t2w2 = (const float*)d_in[18];
    const float* t2b2 = (const float*)d_in[19];
    const float* t2g2 = (const float*)d_in[20];
    const float* t2be2= (const float*)d_in[21];
    const float* c0w  = (const float*)d_in[22];
    const float* c0b  = (const float*)d_in[23];
    const float* c1w1 = (const float*)d_in[24];
    const float* c1b1 = (const float*)d_in[25];
    const float* c1g1 = (const float*)d_in[26];
    const float* c1be1= (const float*)d_in[27];
    const float* c1w2 = (const float*)d_in[28];
    const float* c1b2 = (const float*)d_in[29];
    const float* c1g2 = (const float*)d_in[30];
    const float* c1be2= (const float*)d_in[31];
    const float* fcw  = (const float*)d_in[32];
    const float* fcb  = (const float*)d_in[33];

    char* ws = (char*)d_ws;
    TY* yws = (TY*)ws;
    TY* zws = (TY*)(ws + (size_t)3 * NB * 288 * sizeof(TY));
    float* stat1 = (float*)(ws + (size_t)3 * NB * 288 * sizeof(TY) + (size_t)3 * NB * 80 * sizeof(TY));
    float* stat2 = stat1 + NSLOT * 96;
    float* bn1   = stat2 + NSLOT * 96;
    float* bn2   = bn1 + 96;

    hipMemsetAsync(stat1, 0, 2 * NSLOT * 96 * sizeof(float), stream);

    kA<TY><<<NB / 8, 512, 0, stream>>>(raw, eegf, fgw1, fgb1, fgw2, fgb2,
                                       t1w1, t1b1, t2w1, t2b1, c0w, c0b, c1w1, c1b1,
                                       yws, stat1);
    kBN<<<1, 64, 0, stream>>>(stat1, t1g1, t1be1, t2g1, t2be1, c1g1, c1be1,
                              1.f / (float)((size_t)NB * 18), bn1);
    kC<TY><<<NB / 8, 512, 0, stream>>>(yws, bn1, t1w2, t1b2, t2w2, t2b2, c1w2, c1b2,
                                       zws, stat2);
    kBN<<<1, 64, 0, stream>>>(stat2, t1g2, t1be2, t2g2, t2be2, c1g2, c1be2,
                              1.f / (float)((size_t)NB * 5), bn2);
    kE<TY><<<NB / 8, 256, 0, stream>>>(zws, bn2, fcw, fcb, (float*)d_out);
}

extern "C" void kernel_launch(void* const* d_in, const int* in_sizes, int n_in,
                              void* d_out, int out_size, void* d_ws, size_t ws_size,
                              hipStream_t stream)
{
    (void)in_sizes; (void)n_in; (void)out_size;
    size_t statBytes = (2 * NSLOT * 96 + 192) * sizeof(float);
    size_t needF32 = ((size_t)3 * NB * 288 + (size_t)3 * NB * 80) * 4 + statBytes;
    if (ws_size >= needF32)
        launch_all<float>(d_in, d_out, d_ws, stream);
    else
        launch_all<bf16>(d_in, d_out, d_ws, stream);
}

// Round 16
// 339.532 us; speedup vs baseline: 1.1365x; 1.1365x over previous
//
#include <hip/hip_runtime.h>
#include <hip/hip_bf16.h>

#define NB 32768
#define NSLOT 64
#define EPS 1e-5f

using bf16 = __hip_bfloat16;
using u32  = unsigned int;
typedef _Float16 h2 __attribute__((ext_vector_type(2)));

// ---------- storage-type helpers (f32 or bf16 workspace) ----------
template<typename TY> __device__ __forceinline__ float ldF(const TY* p, size_t i);
template<> __device__ __forceinline__ float ldF<float>(const float* p, size_t i){ return p[i]; }
template<> __device__ __forceinline__ float ldF<bf16 >(const bf16*  p, size_t i){ return __bfloat162float(p[i]); }
template<typename TY> __device__ __forceinline__ void stF(TY* p, size_t i, float v);
template<> __device__ __forceinline__ void stF<float>(float* p, size_t i, float v){ p[i] = v; }
template<> __device__ __forceinline__ void stF<bf16 >(bf16*  p, size_t i, float v){ p[i] = __float2bfloat16(v); }

// f16 pair dot with f32 accumulate
__device__ __forceinline__ float DOT2(u32 a, u32 b, float c){
#if __has_builtin(__builtin_amdgcn_fdot2)
    union { u32 u; h2 h; } ua, ub; ua.u = a; ub.u = b;
    return __builtin_amdgcn_fdot2(ua.h, ub.h, c, false);
#else
    union { u32 u; _Float16 h[2]; } ua, ub; ua.u = a; ub.u = b;
    return c + (float)ua.h[0]*(float)ub.h[0] + (float)ua.h[1]*(float)ub.h[1];
#endif
}
__device__ __forceinline__ float dot8(uint4 e, uint4 w, float acc){
    acc = DOT2(e.x, w.x, acc); acc = DOT2(e.y, w.y, acc);
    acc = DOT2(e.z, w.z, acc); acc = DOT2(e.w, w.w, acc);
    return acc;
}

// y workspace layout (per tau, per sample): slot = k*64 + tg*16 + o, t = 4*k + tg.
// Lane l = tg*16+o stores slot k*64+l -> contiguous wave stores.

// wlU word offsets (f16 packed, rows padded to 16 halves with ZEROS).
#define W1W 0       // t1w1T [16 o][6 kh][8dw], o-stride 52dw
#define W2W 832     // t2w1T [16 o][3 j ][8dw], o-stride 28dw
#define W3W 1280    // c1w1T [16 o][5 kh][8dw], o-stride 44dw
#define C0W 1984    // c0wT  [9 d][8dw]
#define WLW 2056

// ---------------- Kernel A: MLP + xcorr + first convs + BN1 stats ----------------
// r14 structure + MLP de-globalized: fgw1 staged f16 in LDS [35 j][85 dw]
// (odd stride -> gcd(85,32)=1, conflict-free), eegf staged f16 pairs per wave.
template<typename TY>
__global__ __launch_bounds__(512)
void kA(const float* __restrict__ raw, const float* __restrict__ eegf,
        const float* __restrict__ fgw1, const float* __restrict__ fgb1,
        const float* __restrict__ fgw2, const float* __restrict__ fgb2,
        const float* __restrict__ t1w1, const float* __restrict__ t1b1,
        const float* __restrict__ t2w1, const float* __restrict__ t2b1,
        const float* __restrict__ c0w,  const float* __restrict__ c0b,
        const float* __restrict__ c1w1, const float* __restrict__ c1b1,
        TY* __restrict__ yws, float* __restrict__ stat1)
{
    __shared__ __align__(16) u32 rawU[8][396];   // f16 [12 c][66 h] (63 used, pad=0)
    __shared__ __align__(16) u32 eTH[8][456];    // f16 [57 t][16 h]: eeg c0..11, later ec d0..8
    __shared__ __align__(16) u32 wlU[WLW];
    __shared__ __align__(16) u32 fgw1H[2975];    // f16 [35 j][85 dw] (84 used)
    __shared__ __align__(16) u32 eegfH[8][84];   // f16 pairs of eegf per sample
    __shared__ float bF[64];                     // B1 0-15, B2 16-31, B3 32-47, C0B 48-56
    __shared__ float h35_s[8][36];
    __shared__ float filt_s[8][8];
    __shared__ u32   filtH[8][4];
    __shared__ float stat_s[96];

    const int tid = threadIdx.x;
    const int l   = tid & 63;
    const int s   = tid >> 6;
    const int gs  = blockIdx.x * 8 + s;

    if (tid < 96) stat_s[tid] = 0.f;
    {
        _Float16* hp = (_Float16*)wlU;
        for (int idx = tid; idx < 1536; idx += 512) {
            int o = idx / 96, r = idx % 96, kh = r >> 4, h = r & 15;
            hp[o * 104 + kh * 16 + h] = (_Float16)((h < 12) ? t1w1[o * 72 + h * 6 + kh] : 0.f);
        }
        for (int idx = tid; idx < 768; idx += 512) {
            int o = idx / 48, r = idx % 48, j = r >> 4, h = r & 15;
            hp[2 * W2W + o * 56 + j * 16 + h] = (_Float16)((h < 12) ? t2w1[o * 36 + h * 3 + j] : 0.f);
        }
        for (int idx = tid; idx < 1280; idx += 512) {
            int o = idx / 80, r = idx % 80, kh = r >> 4, h = r & 15;
            hp[2 * W3W + o * 88 + kh * 16 + h] = (_Float16)((h < 9) ? c1w1[o * 45 + kh * 9 + h] : 0.f);
        }
        for (int idx = tid; idx < 144; idx += 512) {
            int d = idx / 16, h = idx & 15;
            hp[2 * C0W + d * 16 + h] = (_Float16)((h < 12) ? c0w[h * 9 + d] : 0.f);
        }
        // fgw1 transposed f16: fgw1H halves [j*170 + i] = fgw1[i*35 + j]
        _Float16* gp = (_Float16*)fgw1H;
        for (int idx = tid; idx < 5880; idx += 512) {
            int i = idx / 35, j = idx - 35 * i;
            gp[j * 170 + i] = (_Float16)fgw1[idx];
        }
        if (tid < 16) { bF[tid] = t1b1[tid]; bF[16 + tid] = t2b1[tid]; bF[32 + tid] = c1b1[tid]; }
        if (tid < 9)  bF[48 + tid] = c0b[tid];
    }
    {
        _Float16* rH = (_Float16*)rawU[s];
        for (int r = l; r < 792; r += 64) {
            int c = r / 66, i = r - c * 66;
            rH[r] = (_Float16)((i < 63) ? raw[(size_t)gs * 756 + c * 63 + i] : 0.f);
        }
        // eegf f16 pairs (wave-private)
        const float* ef = eegf + (size_t)gs * 168;
        for (int m = l; m < 84; m += 64) {
            union { u32 u; _Float16 h[2]; } pk;
            pk.h[0] = (_Float16)ef[2 * m];
            pk.h[1] = (_Float16)ef[2 * m + 1];
            eegfH[s][m] = pk.u;
        }
    }
    __syncthreads();

    // ---- MLP: h35 = tanh(eegf @ fg_w1 + b1)  (LDS f16 dot2; wave-synchronous) ----
    if (l < 35) {
        const u32* wj = fgw1H + l * 85;
        const u32* ep = eegfH[s];
        float a0 = 0.f, a1 = 0.f, a2 = 0.f, a3 = 0.f;
        #pragma unroll 2
        for (int m = 0; m < 84; m += 4) {
            a0 = DOT2(ep[m],     wj[m],     a0);
            a1 = DOT2(ep[m + 1], wj[m + 1], a1);
            a2 = DOT2(ep[m + 2], wj[m + 2], a2);
            a3 = DOT2(ep[m + 3], wj[m + 3], a3);
        }
        h35_s[s][l] = tanhf(a0 + a1 + a2 + a3 + fgb1[l]);
    }
    if (l < 7) {
        float a = fgb2[l];
        for (int j = 0; j < 35; ++j) a = fmaf(h35_s[s][j], fgw2[j * 7 + l], a);
        filt_s[s][l] = tanhf(a);
    }
    if (l == 7) filt_s[s][7] = 0.f;
    if (l < 4) {
        union { u32 u; _Float16 h[2]; } pk;
        pk.h[0] = (_Float16)filt_s[s][2 * l];
        pk.h[1] = (_Float16)filt_s[s][2 * l + 1];
        filtH[s][l] = pk.u;
    }

    const int o = l & 15, tg = l >> 4;      // t = tg + 4k; k=4 valid only for tg<2
    const bool k4 = (tg < 2);

    {
        const u32 fp0 = filtH[s][0], fp1 = filtH[s][1], fp2 = filtH[s][2], fp3 = filtH[s][3];
        const int cc = l & 15;
        const u32* rw = rawU[s] + (cc < 12 ? cc : 0) * 33;
        const u32 sh = (u32)(tg & 1) * 16;
        _Float16* eH = (_Float16*)eTH[s];
        #pragma unroll 3
        for (int j = 0; j < 15; ++j) {
            int t = tg + 4 * j;
            if (t < 57) {
                const u32* p = rw + (t >> 1);
                u32 w0 = p[0], w1 = p[1], w2 = p[2], w3 = p[3], w4 = p[4];
                u32 u0 = __builtin_amdgcn_alignbit(w1, w0, sh);
                u32 u1 = __builtin_amdgcn_alignbit(w2, w1, sh);
                u32 u2 = __builtin_amdgcn_alignbit(w3, w2, sh);
                u32 u3 = __builtin_amdgcn_alignbit(w4, w3, sh);
                float v = DOT2(u3, fp3, 0.f);
                v = DOT2(u2, fp2, v); v = DOT2(u1, fp1, v); v = DOT2(u0, fp0, v);
                if (cc >= 12) v = 0.f;
                eH[t * 16 + cc] = (_Float16)v;
            }
        }
    }

    // ---- tau=0 + tau=1 FUSED: t2 accumulates on t1's even-kh data reads ----
    {
        const float b1v = bF[o], b2v = bF[16 + o];
        float a0 = b1v, a1 = b1v, a2 = b1v, a3 = b1v, a4 = b1v;
        float g0 = b2v, g1 = b2v, g2 = b2v, g3 = b2v, g4 = b2v;
        const u32* w1b = wlU + W1W + o * 52;
        const u32* w2b = wlU + W2W + o * 28;
        const u32* eU  = eTH[s];
        #pragma unroll 2
        for (int kh = 0; kh < 6; ++kh) {
            const uint4 wa = *(const uint4*)(w1b + kh * 8);
            const uint4 wb = *(const uint4*)(w1b + kh * 8 + 4);
            const bool ev = (kh & 1) == 0;
            uint4 va, vb;
            if (ev) { va = *(const uint4*)(w2b + (kh >> 1) * 8); vb = *(const uint4*)(w2b + (kh >> 1) * 8 + 4); }
            const u32* r = eU + (3 * tg + kh) * 8;
            uint4 ea, eb;
            ea = *(const uint4*)(r);       eb = *(const uint4*)(r + 4);
            a0 = dot8(eb, wb, dot8(ea, wa, a0));
            if (ev) g0 = dot8(eb, vb, dot8(ea, va, g0));
            ea = *(const uint4*)(r + 96);  eb = *(const uint4*)(r + 100);
            a1 = dot8(eb, wb, dot8(ea, wa, a1));
            if (ev) g1 = dot8(eb, vb, dot8(ea, va, g1));
            ea = *(const uint4*)(r + 192); eb = *(const uint4*)(r + 196);
            a2 = dot8(eb, wb, dot8(ea, wa, a2));
            if (ev) g2 = dot8(eb, vb, dot8(ea, va, g2));
            ea = *(const uint4*)(r + 288); eb = *(const uint4*)(r + 292);
            a3 = dot8(eb, wb, dot8(ea, wa, a3));
            if (ev) g3 = dot8(eb, vb, dot8(ea, va, g3));
            if (k4) {
                ea = *(const uint4*)(r + 384); eb = *(const uint4*)(r + 388);
                a4 = dot8(eb, wb, dot8(ea, wa, a4));
                if (ev) g4 = dot8(eb, vb, dot8(ea, va, g4));
            }
        }
        size_t base = (size_t)gs * 288 + l;
        stF<TY>(yws, base,       a0); stF<TY>(yws, base + 64,  a1);
        stF<TY>(yws, base + 128, a2); stF<TY>(yws, base + 192, a3);
        float sum = a0 + a1 + a2 + a3;
        float sq  = fmaf(a0, a0, fmaf(a1, a1, fmaf(a2, a2, a3 * a3)));
        if (k4) { stF<TY>(yws, base + 256, a4); sum += a4; sq = fmaf(a4, a4, sq); }
        sum += __shfl_xor(sum, 16); sq += __shfl_xor(sq, 16);
        sum += __shfl_xor(sum, 32); sq += __shfl_xor(sq, 32);
        if (tg == 0) { atomicAdd(&stat_s[o * 2], sum); atomicAdd(&stat_s[o * 2 + 1], sq); }
        base = (size_t)NB * 288 + (size_t)gs * 288 + l;
        stF<TY>(yws, base,       g0); stF<TY>(yws, base + 64,  g1);
        stF<TY>(yws, base + 128, g2); stF<TY>(yws, base + 192, g3);
        sum = g0 + g1 + g2 + g3;
        sq  = fmaf(g0, g0, fmaf(g1, g1, fmaf(g2, g2, g3 * g3)));
        if (k4) { stF<TY>(yws, base + 256, g4); sum += g4; sq = fmaf(g4, g4, sq); }
        sum += __shfl_xor(sum, 16); sq += __shfl_xor(sq, 16);
        sum += __shfl_xor(sum, 32); sq += __shfl_xor(sq, 32);
        if (tg == 0) { atomicAdd(&stat_s[32 + o * 2], sum); atomicAdd(&stat_s[32 + o * 2 + 1], sq); }
    }

    if (l < 63) {
        const int dd = l % 9, tc = l / 9;
        const u32* cw = wlU + C0W + dd * 8;
        const uint4 wca = *(const uint4*)(cw);
        const uint2 wcb = *(const uint2*)(cw + 4);
        const float cb  = bF[48 + dd];
        _Float16* eH = (_Float16*)eTH[s];
        const u32* eU = eTH[s];
        #pragma unroll 3
        for (int j = 0; j < 9; ++j) {
            int t = tc + 7 * j;
            if (t < 57) {
                const u32* r = eU + t * 8;
                uint4 ea = *(const uint4*)r;
                uint2 eb = *(const uint2*)(r + 4);
                float a = dot8(ea, wca, cb);
                a = DOT2(eb.x, wcb.x, a); a = DOT2(eb.y, wcb.y, a);
                eH[t * 16 + dd] = (_Float16)fmaxf(a, 0.f);
            }
        }
    }
    {
        _Float16* eH = (_Float16*)eTH[s];
        for (int m = l; m < 171; m += 64) { int t = m / 3, dd2 = 9 + m % 3; eH[t * 16 + dd2] = (_Float16)0.f; }
    }

    {
        const float b3v = bF[32 + o];
        float a0 = b3v, a1 = b3v, a2 = b3v, a3 = b3v, a4 = b3v;
        const u32* w3b = wlU + W3W + o * 44;
        const u32* eU  = eTH[s];
        #pragma unroll 2
        for (int kh = 0; kh < 5; ++kh) {
            const uint4 wa = *(const uint4*)(w3b + kh * 8);
            const uint2 wb = *(const uint2*)(w3b + kh * 8 + 4);
            const u32* r = eU + (3 * tg + kh) * 8;
            uint4 ea; uint2 eb;
            ea = *(const uint4*)(r);       eb = *(const uint2*)(r + 4);
            a0 = dot8(ea, wa, a0); a0 = DOT2(eb.x, wb.x, a0); a0 = DOT2(eb.y, wb.y, a0);
            ea = *(const uint4*)(r + 96);  eb = *(const uint2*)(r + 100);
            a1 = dot8(ea, wa, a1); a1 = DOT2(eb.x, wb.x, a1); a1 = DOT2(eb.y, wb.y, a1);
            ea = *(const uint4*)(r + 192); eb = *(const uint2*)(r + 196);
            a2 = dot8(ea, wa, a2); a2 = DOT2(eb.x, wb.x, a2); a2 = DOT2(eb.y, wb.y, a2);
            ea = *(const uint4*)(r + 288); eb = *(const uint2*)(r + 292);
            a3 = dot8(ea, wa, a3); a3 = DOT2(eb.x, wb.x, a3); a3 = DOT2(eb.y, wb.y, a3);
            if (k4) {
                ea = *(const uint4*)(r + 384); eb = *(const uint2*)(r + 388);
                a4 = dot8(ea, wa, a4); a4 = DOT2(eb.x, wb.x, a4); a4 = DOT2(eb.y, wb.y, a4);
            }
        }
        size_t base = (size_t)2 * NB * 288 + (size_t)gs * 288 + l;
        stF<TY>(yws, base,       a0); stF<TY>(yws, base + 64,  a1);
        stF<TY>(yws, base + 128, a2); stF<TY>(yws, base + 192, a3);
        float sum = a0 + a1 + a2 + a3;
        float sq  = fmaf(a0, a0, fmaf(a1, a1, fmaf(a2, a2, a3 * a3)));
        if (k4) { stF<TY>(yws, base + 256, a4); sum += a4; sq = fmaf(a4, a4, sq); }
        sum += __shfl_xor(sum, 16); sq += __shfl_xor(sq, 16);
        sum += __shfl_xor(sum, 32); sq += __shfl_xor(sq, 32);
        if (tg == 0) { atomicAdd(&stat_s[64 + o * 2], sum); atomicAdd(&stat_s[64 + o * 2 + 1], sq); }
    }
    __syncthreads();
    if (tid < 96) atomicAdd(&stat1[(blockIdx.x & (NSLOT - 1)) * 96 + tid], stat_s[tid]);
}

// ---------------- BN finalize (stage 1 or 2) ----------------
__global__ void kBN(const float* __restrict__ statp,
                    const float* __restrict__ g0, const float* __restrict__ be0,
                    const float* __restrict__ g1, const float* __restrict__ be1,
                    const float* __restrict__ g2, const float* __restrict__ be2,
                    float nInv, float* __restrict__ bnp)
{
    int tid = threadIdx.x;
    if (tid >= 48) return;
    int tau = tid / 16, o = tid % 16;
    float sum = 0.f, sq = 0.f;
    for (int sl = 0; sl < NSLOT; ++sl) {
        sum += statp[sl * 96 + tid * 2];
        sq  += statp[sl * 96 + tid * 2 + 1];
    }
    float mean = sum * nInv;
    float var  = sq * nInv - mean * mean;
    const float* g  = (tau == 0) ? g0 : (tau == 1) ? g1 : g2;
    const float* be = (tau == 0) ? be0 : (tau == 1) ? be1 : be2;
    float scale = g[o] / sqrtf(var + EPS);
    float shift = be[o] - mean * scale;
    bnp[tid * 2]     = scale;
    bnp[tid * 2 + 1] = shift;
}

// ---------------- Kernel C: BN1+relu, second convs (f16/dot2), BN2 stats ----------------
#define C_W1 0      // [16 o][6 kh][8dw], o-stride 52
#define C_W2 832    // [16 o][3 j ][8dw], o-stride 28
#define C_W3 1280   // [16 o][5 kh][8dw], o-stride 44
#define C_WL 1984

template<typename TY>
__global__ __launch_bounds__(512)
void kC(const TY* __restrict__ yws, const float* __restrict__ bn1,
        const float* __restrict__ t1w2, const float* __restrict__ t1b2,
        const float* __restrict__ t2w2, const float* __restrict__ t2b2,
        const float* __restrict__ c1w2, const float* __restrict__ c1b2,
        TY* __restrict__ zws, float* __restrict__ stat2)
{
    __shared__ __align__(16) u32 hT[3][8][144];   // f16 [18 t][8 dw] per tau,sample
    __shared__ __align__(16) u32 wl2[C_WL];
    __shared__ float bB[48];
    __shared__ float bnp[96];
    __shared__ float stat_s[96];

    const int tid = threadIdx.x;
    const int l   = tid & 63;
    const int s   = tid >> 6;
    const int gs  = blockIdx.x * 8 + s;

    if (tid < 96) { stat_s[tid] = 0.f; bnp[tid] = bn1[tid]; }
    {
        _Float16* hp = (_Float16*)wl2;
        for (int idx = tid; idx < 1536; idx += 512) { int o = idx / 96, r = idx % 96, kh = r >> 4, c = r & 15;
            hp[o * 104 + kh * 16 + c] = (_Float16)t1w2[o * 96 + c * 6 + kh]; }
        for (int idx = tid; idx < 768; idx += 512) { int o = idx / 48, r = idx % 48, j = r >> 4, c = r & 15;
            hp[2 * C_W2 + o * 56 + j * 16 + c] = (_Float16)t2w2[o * 48 + c * 3 + j]; }
        for (int idx = tid; idx < 1280; idx += 512) { int o = idx / 80, r = idx % 80, kh = r >> 4, c = r & 15;
            hp[2 * C_W3 + o * 88 + kh * 16 + c] = (_Float16)c1w2[o * 80 + c * 5 + kh]; }
        if (tid < 16) { bB[tid] = t1b2[tid]; bB[16 + tid] = t2b2[tid]; bB[32 + tid] = c1b2[tid]; }
    }
    __syncthreads();

    const int o = l & 15, tg = l >> 4;
    const bool k4 = (tg == 0);

    #pragma unroll
    for (int tau = 0; tau < 3; ++tau) {
        const float sc = bnp[(tau * 16 + o) * 2], sh = bnp[(tau * 16 + o) * 2 + 1];
        _Float16* hH = (_Float16*)hT[tau][s];
        const size_t yb = (size_t)tau * NB * 288 + (size_t)gs * 288 + l;
        #pragma unroll
        for (int k = 0; k < 4; ++k) {
            float v = ldF<TY>(yws, yb + k * 64);
            hH[(4 * k + tg) * 16 + o] = (_Float16)fmaxf(fmaf(v, sc, sh), 0.f);
        }
        if (l < 32) {
            float v = ldF<TY>(yws, yb + 256);
            hH[(16 + tg) * 16 + o] = (_Float16)fmaxf(fmaf(v, sc, sh), 0.f);
        }
    }

    {
        const float b = bB[o];
        float a0 = b, a1 = b;
        const u32* w = wl2 + C_W1 + o * 52;
        const u32* h0 = hT[0][s];
        #pragma unroll 2
        for (int kh = 0; kh < 6; ++kh) {
            const uint4 wa = *(const uint4*)(w + kh * 8);
            const uint4 wb = *(const uint4*)(w + kh * 8 + 4);
            const u32* r = h0 + (3 * tg + kh) * 8;
            uint4 ea = *(const uint4*)r, eb = *(const uint4*)(r + 4);
            a0 = dot8(eb, wb, dot8(ea, wa, a0));
            if (k4) {
                const u32* r2 = h0 + (12 + kh) * 8;
                uint4 fa = *(const uint4*)r2, fb = *(const uint4*)(r2 + 4);
                a1 = dot8(fb, wb, dot8(fa, wa, a1));
            }
        }
        size_t zb = (size_t)gs * 80;
        stF<TY>(zws, zb + o * 5 + tg, a0);
        float sum = a0, sq = a0 * a0;
        if (k4) { stF<TY>(zws, zb + o * 5 + 4, a1); sum += a1; sq = fmaf(a1, a1, sq); }
        sum += __shfl_xor(sum, 16); sq += __shfl_xor(sq, 16);
        sum += __shfl_xor(sum, 32); sq += __shfl_xor(sq, 32);
        if (tg == 0) { atomicAdd(&stat_s[o * 2], sum); atomicAdd(&stat_s[o * 2 + 1], sq); }
    }

    {
        const float b = bB[16 + o];
        float a0 = b, a1 = b;
        const u32* w = wl2 + C_W2 + o * 28;
        const u32* h1 = hT[1][s];
        #pragma unroll
        for (int j = 0; j < 3; ++j) {
            const uint4 wa = *(const uint4*)(w + j * 8);
            const uint4 wb = *(const uint4*)(w + j * 8 + 4);
            const u32* r = h1 + (3 * tg + 2 * j) * 8;
            uint4 ea = *(const uint4*)r, eb = *(const uint4*)(r + 4);
            a0 = dot8(eb, wb, dot8(ea, wa, a0));
            if (k4) {
                const u32* r2 = h1 + (12 + 2 * j) * 8;
                uint4 fa = *(const uint4*)r2, fb = *(const uint4*)(r2 + 4);
                a1 = dot8(fb, wb, dot8(fa, wa, a1));
            }
        }
        size_t zb = (size_t)NB * 80 + (size_t)gs * 80;
        stF<TY>(zws, zb + o * 5 + tg, a0);
        float sum = a0, sq = a0 * a0;
        if (k4) { stF<TY>(zws, zb + o * 5 + 4, a1); sum += a1; sq = fmaf(a1, a1, sq); }
        sum += __shfl_xor(sum, 16); sq += __shfl_xor(sq, 16);
        sum += __shfl_xor(sum, 32); sq += __shfl_xor(sq, 32);
        if (tg == 0) { atomicAdd(&stat_s[32 + o * 2], sum); atomicAdd(&stat_s[32 + o * 2 + 1], sq); }
    }

    {
        const float b = bB[32 + o];
        float a0 = b, a1 = b;
        const u32* w = wl2 + C_W3 + o * 44;
        const u32* h2 = hT[2][s];
        #pragma unroll 2
        for (int kh = 0; kh < 5; ++kh) {
            const uint4 wa = *(const uint4*)(w + kh * 8);
            const uint4 wb = *(const uint4*)(w + kh * 8 + 4);
            const u32* r = h2 + (3 * tg + kh) * 8;
            uint4 ea = *(const uint4*)r, eb = *(const uint4*)(r + 4);
            a0 = dot8(eb, wb, dot8(ea, wa, a0));
            if (k4) {
                const u32* r2 = h2 + (12 + kh) * 8;
                uint4 fa = *(const uint4*)r2, fb = *(const uint4*)(r2 + 4);
                a1 = dot8(fb, wb, dot8(fa, wa, a1));
            }
        }
        size_t zb = (size_t)2 * NB * 80 + (size_t)gs * 80;
        stF<TY>(zws, zb + o * 5 + tg, a0);
        float sum = a0, sq = a0 * a0;
        if (k4) { stF<TY>(zws, zb + o * 5 + 4, a1); sum += a1; sq = fmaf(a1, a1, sq); }
        sum += __shfl_xor(sum, 16); sq += __shfl_xor(sq, 16);
        sum += __shfl_xor(sum, 32); sq += __shfl_xor(sq, 32);
        if (tg == 0) { atomicAdd(&stat_s[64 + o * 2], sum); atomicAdd(&stat_s[64 + o * 2 + 1], sq); }
    }
    __syncthreads();
    if (tid < 96) atomicAdd(&stat2[(blockIdx.x & (NSLOT - 1)) * 96 + tid], stat_s[tid]);
}

// ---------------- Kernel E: BN2+relu, feats, FC (f16 dot2), tanh ----------------
template<typename TY>
__global__ __launch_bounds__(256)
void kE(const TY* __restrict__ zws, const float* __restrict__ bn2,
        const float* __restrict__ fcw, const float* __restrict__ fcb,
        float* __restrict__ out)
{
    __shared__ __align__(16) u32 fcwH[8000];
    __shared__ __align__(16) u32 featsH[8][160];
    __shared__ float fcb_s[50];
    __shared__ float bnp[96];
    const int tid = threadIdx.x;
    const int s0  = blockIdx.x * 8;

    if (tid < 96) bnp[tid] = bn2[tid];
    if (tid < 50) fcb_s[tid] = fcb[tid];
    for (int idx = tid; idx < 8000; idx += 256) {
        int fp = idx / 50, u = idx % 50;
        union { u32 v; _Float16 h[2]; } pk;
        pk.h[0] = (_Float16)fcw[(2 * fp) * 50 + u];
        pk.h[1] = (_Float16)fcw[(2 * fp + 1) * 50 + u];
        fcwH[idx] = pk.v;
    }
    __syncthreads();

    for (int idx = tid; idx < 2560; idx += 256) {
        int s = idx / 320, f = idx % 320;
        int g = f / 80; int tau = (g == 3) ? 2 : g;
        int r = f % 80, o = r / 5;
        float v = ldF<TY>(zws, (size_t)tau * NB * 80 + (size_t)(s0 + s) * 80 + r);
        float x = fmaxf(fmaf(v, bnp[(tau * 16 + o) * 2], bnp[(tau * 16 + o) * 2 + 1]), 0.f);
        ((_Float16*)featsH[s])[f] = (_Float16)x;
    }
    __syncthreads();

    const int sA = tid / 50, uA = tid % 50;
    const int iB = tid + 256, sB = iB / 50, uB = iB % 50;
    float accA = fcb_s[uA];
    float accB = (tid < 144) ? fcb_s[uB] : 0.f;
    #pragma unroll 4
    for (int fp = 0; fp < 160; ++fp) {
        u32 w1 = fcwH[fp * 50 + uA];
        u32 x1 = featsH[sA][fp];
        accA = DOT2(x1, w1, accA);
        if (tid < 144) {
            u32 w2 = fcwH[fp * 50 + uB];
            u32 x2 = featsH[sB][fp];
            accB = DOT2(x2, w2, accB);
        }
    }
    out[(size_t)(s0 + sA) * 50 + uA] = tanhf(accA);
    if (tid < 144) out[(size_t)(s0 + sB) * 50 + uB] = tanhf(accB);
}

// ---------------- host launcher ----------------
template<typename TY>
static void launch_all(void* const* d_in, void* d_out, void* d_ws, hipStream_t stream)
{
    const float* raw  = (const float*)d_in[0];
    const float* eegf = (const float*)d_in[1];
    const float* fgw1 = (const float*)d_in[2];
    const float* fgb1 = (const float*)d_in[3];
    const float* fgw2 = (const float*)d_in[4];
    const float* fgb2 = (const float*)d_in[5];
    const float* t1w1 = (const float*)d_in[6];
    const float* t1b1 = (const float*)d_in[7];
    const float* t1g1 = (const float*)d_in[8];
    const float* t1be1= (const float*)d_in[9];
    const float* t1w2 = (const float*)d_in[10];
    const float* t1b2 = (const float*)d_in[11];
    const float* t1g2 = (const float*)d_in[12];
    const float* t1be2= (const float*)d_in[13];
    const float* t2w1 = (const float*)d_in[14];
    const float* t2b1 = (const float*)d_in[15];
    const float* t2g1 = (const float*)d_in[16];
    const float* t2be1= (const float*)d_in[17];
    const float* t2w2 = (const float*)d_in[18];
    const float* t2b2 = (const float*)d_in[19];
    const float* t2g2 = (const float*)d_in[20];
    const float* t2be2= (const float*)d_in[21];
    const float* c0w  = (const float*)d_in[22];
    const float* c0b  = (const float*)d_in[23];
    const float* c1w1 = (const float*)d_in[24];
    const float* c1b1 = (const float*)d_in[25];
    const float* c1g1 = (const float*)d_in[26];
    const float* c1be1= (const float*)d_in[27];
    const float* c1w2 = (const float*)d_in[28];
    const float* c1b2 = (const float*)d_in[29];
    const float* c1g2 = (const float*)d_in[30];
    const float* c1be2= (const float*)d_in[31];
    const float* fcw  = (const float*)d_in[32];
    const float* fcb  = (const float*)d_in[33];

    char* ws = (char*)d_ws;
    TY* yws = (TY*)ws;
    TY* zws = (TY*)(ws + (size_t)3 * NB * 288 * sizeof(TY));
    float* stat1 = (float*)(ws + (size_t)3 * NB * 288 * sizeof(TY) + (size_t)3 * NB * 80 * sizeof(TY));
    float* stat2 = stat1 + NSLOT * 96;
    float* bn1   = stat2 + NSLOT * 96;
    float* bn2   = bn1 + 96;

    hipMemsetAsync(stat1, 0, 2 * NSLOT * 96 * sizeof(float), stream);

    kA<TY><<<NB / 8, 512, 0, stream>>>(raw, eegf, fgw1, fgb1, fgw2, fgb2,
                                       t1w1, t1b1, t2w1, t2b1, c0w, c0b, c1w1, c1b1,
                                       yws, stat1);
    kBN<<<1, 64, 0, stream>>>(stat1, t1g1, t1be1, t2g1, t2be1, c1g1, c1be1,
                              1.f / (float)((size_t)NB * 18), bn1);
    kC<TY><<<NB / 8, 512, 0, stream>>>(yws, bn1, t1w2, t1b2, t2w2, t2b2, c1w2, c1b2,
                                       zws, stat2);
    kBN<<<1, 64, 0, stream>>>(stat2, t1g2, t1be2, t2g2, t2be2, c1g2, c1be2,
                              1.f / (float)((size_t)NB * 5), bn2);
    kE<TY><<<NB / 8, 256, 0, stream>>>(zws, bn2, fcw, fcb, (float*)d_out);
}

extern "C" void kernel_launch(void* const* d_in, const int* in_sizes, int n_in,
                              void* d_out, int out_size, void* d_ws, size_t ws_size,
                              hipStream_t stream)
{
    (void)in_sizes; (void)n_in; (void)out_size;
    size_t statBytes = (2 * NSLOT * 96 + 192) * sizeof(float);
    size_t needF32 = ((size_t)3 * NB * 288 + (size_t)3 * NB * 80) * 4 + statBytes;
    if (ws_size >= needF32)
        launch_all<float>(d_in, d_out, d_ws, stream);
    else
        launch_all<bf16>(d_in, d_out, d_ws, stream);
}

// Round 17
// 327.326 us; speedup vs baseline: 1.1789x; 1.0373x over previous
//
#include <hip/hip_runtime.h>
#include <hip/hip_bf16.h>

#define NB 32768
#define NSLOT 64
#define EPS 1e-5f

using bf16 = __hip_bfloat16;
using u32  = unsigned int;
typedef _Float16 h2 __attribute__((ext_vector_type(2)));

// ---------- storage-type helpers (f32 or bf16 workspace) ----------
template<typename TY> __device__ __forceinline__ float ldF(const TY* p, size_t i);
template<> __device__ __forceinline__ float ldF<float>(const float* p, size_t i){ return p[i]; }
template<> __device__ __forceinline__ float ldF<bf16 >(const bf16*  p, size_t i){ return __bfloat162float(p[i]); }
template<typename TY> __device__ __forceinline__ void stF(TY* p, size_t i, float v);
template<> __device__ __forceinline__ void stF<float>(float* p, size_t i, float v){ p[i] = v; }
template<> __device__ __forceinline__ void stF<bf16 >(bf16*  p, size_t i, float v){ p[i] = __float2bfloat16(v); }

// f16 pair dot with f32 accumulate
__device__ __forceinline__ float DOT2(u32 a, u32 b, float c){
#if __has_builtin(__builtin_amdgcn_fdot2)
    union { u32 u; h2 h; } ua, ub; ua.u = a; ub.u = b;
    return __builtin_amdgcn_fdot2(ua.h, ub.h, c, false);
#else
    union { u32 u; _Float16 h[2]; } ua, ub; ua.u = a; ub.u = b;
    return c + (float)ua.h[0]*(float)ub.h[0] + (float)ua.h[1]*(float)ub.h[1];
#endif
}
__device__ __forceinline__ float dot8(uint4 e, uint4 w, float acc){
    acc = DOT2(e.x, w.x, acc); acc = DOT2(e.y, w.y, acc);
    acc = DOT2(e.z, w.z, acc); acc = DOT2(e.w, w.w, acc);
    return acc;
}

// y workspace layout (per tau, per sample): slot = k*64 + tg*16 + o, t = 4*k + tg.
// Lane l = tg*16+o stores slot k*64+l -> contiguous wave stores.

// wlU word offsets (f16 packed, rows padded to 16 halves with ZEROS).
#define W1W 0       // t1w1T [16 o][6 kh][8dw], o-stride 52dw
#define W2W 832     // t2w1T [16 o][3 j ][8dw], o-stride 28dw
#define W3W 1280    // c1w1T [16 o][5 kh][8dw], o-stride 44dw
#define C0W 1984    // c0wT  [9 d][8dw]
#define WLW 2056

// ---------------- Kernel A: MLP + xcorr + first convs + BN1 stats ----------------
template<typename TY>
__global__ __launch_bounds__(512)
void kA(const float* __restrict__ raw, const float* __restrict__ eegf,
        const float* __restrict__ fgw1, const float* __restrict__ fgb1,
        const float* __restrict__ fgw2, const float* __restrict__ fgb2,
        const float* __restrict__ t1w1, const float* __restrict__ t1b1,
        const float* __restrict__ t2w1, const float* __restrict__ t2b1,
        const float* __restrict__ c0w,  const float* __restrict__ c0b,
        const float* __restrict__ c1w1, const float* __restrict__ c1b1,
        TY* __restrict__ yws, float* __restrict__ stat1)
{
    __shared__ __align__(16) u32 rawU[8][396];   // f16 [12 c][66 h] (63 used, pad=0)
    __shared__ __align__(16) u32 eTH[8][456];    // f16 [57 t][16 h]: eeg c0..11, later ec d0..8
    __shared__ __align__(16) u32 wlU[WLW];
    __shared__ __align__(16) u32 fgw1H[2975];    // f16 [35 j][85 dw] (84 used)
    __shared__ __align__(16) u32 eegfH[8][84];   // f16 pairs of eegf per sample
    __shared__ float bF[64];                     // B1 0-15, B2 16-31, B3 32-47, C0B 48-56
    __shared__ float h35_s[8][36];
    __shared__ float filt_s[8][8];
    __shared__ u32   filtH[8][4];
    __shared__ float stat_s[96];

    const int tid = threadIdx.x;
    const int l   = tid & 63;
    const int s   = tid >> 6;
    const int gs  = blockIdx.x * 8 + s;

    if (tid < 96) stat_s[tid] = 0.f;
    {
        _Float16* hp = (_Float16*)wlU;
        for (int idx = tid; idx < 1536; idx += 512) {
            int o = idx / 96, r = idx % 96, kh = r >> 4, h = r & 15;
            hp[o * 104 + kh * 16 + h] = (_Float16)((h < 12) ? t1w1[o * 72 + h * 6 + kh] : 0.f);
        }
        for (int idx = tid; idx < 768; idx += 512) {
            int o = idx / 48, r = idx % 48, j = r >> 4, h = r & 15;
            hp[2 * W2W + o * 56 + j * 16 + h] = (_Float16)((h < 12) ? t2w1[o * 36 + h * 3 + j] : 0.f);
        }
        for (int idx = tid; idx < 1280; idx += 512) {
            int o = idx / 80, r = idx % 80, kh = r >> 4, h = r & 15;
            hp[2 * W3W + o * 88 + kh * 16 + h] = (_Float16)((h < 9) ? c1w1[o * 45 + kh * 9 + h] : 0.f);
        }
        for (int idx = tid; idx < 144; idx += 512) {
            int d = idx / 16, h = idx & 15;
            hp[2 * C0W + d * 16 + h] = (_Float16)((h < 12) ? c0w[h * 9 + d] : 0.f);
        }
        // fgw1 transposed f16, staged j-major: consecutive tid -> consecutive halves
        _Float16* gp = (_Float16*)fgw1H;
        for (int idx = tid; idx < 5880; idx += 512) {
            int j = idx / 168, i = idx - 168 * j;
            gp[j * 170 + i] = (_Float16)fgw1[i * 35 + j];
        }
        if (tid < 16) { bF[tid] = t1b1[tid]; bF[16 + tid] = t2b1[tid]; bF[32 + tid] = c1b1[tid]; }
        if (tid < 9)  bF[48 + tid] = c0b[tid];
    }
    {
        _Float16* rH = (_Float16*)rawU[s];
        for (int r = l; r < 792; r += 64) {
            int c = r / 66, i = r - c * 66;
            rH[r] = (_Float16)((i < 63) ? raw[(size_t)gs * 756 + c * 63 + i] : 0.f);
        }
        const float* ef = eegf + (size_t)gs * 168;
        for (int m = l; m < 84; m += 64) {
            union { u32 u; _Float16 h[2]; } pk;
            pk.h[0] = (_Float16)ef[2 * m];
            pk.h[1] = (_Float16)ef[2 * m + 1];
            eegfH[s][m] = pk.u;
        }
    }
    __syncthreads();

    if (l < 35) {
        const u32* wj = fgw1H + l * 85;
        const u32* ep = eegfH[s];
        float a0 = 0.f, a1 = 0.f, a2 = 0.f, a3 = 0.f;
        #pragma unroll 2
        for (int m = 0; m < 84; m += 4) {
            a0 = DOT2(ep[m],     wj[m],     a0);
            a1 = DOT2(ep[m + 1], wj[m + 1], a1);
            a2 = DOT2(ep[m + 2], wj[m + 2], a2);
            a3 = DOT2(ep[m + 3], wj[m + 3], a3);
        }
        h35_s[s][l] = tanhf(a0 + a1 + a2 + a3 + fgb1[l]);
    }
    if (l < 7) {
        float a = fgb2[l];
        for (int j = 0; j < 35; ++j) a = fmaf(h35_s[s][j], fgw2[j * 7 + l], a);
        filt_s[s][l] = tanhf(a);
    }
    if (l == 7) filt_s[s][7] = 0.f;
    if (l < 4) {
        union { u32 u; _Float16 h[2]; } pk;
        pk.h[0] = (_Float16)filt_s[s][2 * l];
        pk.h[1] = (_Float16)filt_s[s][2 * l + 1];
        filtH[s][l] = pk.u;
    }

    const int o = l & 15, tg = l >> 4;      // t = tg + 4k; k=4 valid only for tg<2
    const bool k4 = (tg < 2);

    {
        const u32 fp0 = filtH[s][0], fp1 = filtH[s][1], fp2 = filtH[s][2], fp3 = filtH[s][3];
        const int cc = l & 15;
        const u32* rw = rawU[s] + (cc < 12 ? cc : 0) * 33;
        const u32 sh = (u32)(tg & 1) * 16;
        _Float16* eH = (_Float16*)eTH[s];
        #pragma unroll 3
        for (int j = 0; j < 15; ++j) {
            int t = tg + 4 * j;
            if (t < 57) {
                const u32* p = rw + (t >> 1);
                u32 w0 = p[0], w1 = p[1], w2 = p[2], w3 = p[3], w4 = p[4];
                u32 u0 = __builtin_amdgcn_alignbit(w1, w0, sh);
                u32 u1 = __builtin_amdgcn_alignbit(w2, w1, sh);
                u32 u2 = __builtin_amdgcn_alignbit(w3, w2, sh);
                u32 u3 = __builtin_amdgcn_alignbit(w4, w3, sh);
                float v = DOT2(u3, fp3, 0.f);
                v = DOT2(u2, fp2, v); v = DOT2(u1, fp1, v); v = DOT2(u0, fp0, v);
                if (cc >= 12) v = 0.f;
                eH[t * 16 + cc] = (_Float16)v;
            }
        }
    }

    // ---- tau=0 + tau=1 FUSED ----
    {
        const float b1v = bF[o], b2v = bF[16 + o];
        float a0 = b1v, a1 = b1v, a2 = b1v, a3 = b1v, a4 = b1v;
        float g0 = b2v, g1 = b2v, g2 = b2v, g3 = b2v, g4 = b2v;
        const u32* w1b = wlU + W1W + o * 52;
        const u32* w2b = wlU + W2W + o * 28;
        const u32* eU  = eTH[s];
        #pragma unroll 2
        for (int kh = 0; kh < 6; ++kh) {
            const uint4 wa = *(const uint4*)(w1b + kh * 8);
            const uint4 wb = *(const uint4*)(w1b + kh * 8 + 4);
            const bool ev = (kh & 1) == 0;
            uint4 va, vb;
            if (ev) { va = *(const uint4*)(w2b + (kh >> 1) * 8); vb = *(const uint4*)(w2b + (kh >> 1) * 8 + 4); }
            const u32* r = eU + (3 * tg + kh) * 8;
            uint4 ea, eb;
            ea = *(const uint4*)(r);       eb = *(const uint4*)(r + 4);
            a0 = dot8(eb, wb, dot8(ea, wa, a0));
            if (ev) g0 = dot8(eb, vb, dot8(ea, va, g0));
            ea = *(const uint4*)(r + 96);  eb = *(const uint4*)(r + 100);
            a1 = dot8(eb, wb, dot8(ea, wa, a1));
            if (ev) g1 = dot8(eb, vb, dot8(ea, va, g1));
            ea = *(const uint4*)(r + 192); eb = *(const uint4*)(r + 196);
            a2 = dot8(eb, wb, dot8(ea, wa, a2));
            if (ev) g2 = dot8(eb, vb, dot8(ea, va, g2));
            ea = *(const uint4*)(r + 288); eb = *(const uint4*)(r + 292);
            a3 = dot8(eb, wb, dot8(ea, wa, a3));
            if (ev) g3 = dot8(eb, vb, dot8(ea, va, g3));
            if (k4) {
                ea = *(const uint4*)(r + 384); eb = *(const uint4*)(r + 388);
                a4 = dot8(eb, wb, dot8(ea, wa, a4));
                if (ev) g4 = dot8(eb, vb, dot8(ea, va, g4));
            }
        }
        size_t base = (size_t)gs * 288 + l;
        stF<TY>(yws, base,       a0); stF<TY>(yws, base + 64,  a1);
        stF<TY>(yws, base + 128, a2); stF<TY>(yws, base + 192, a3);
        float sum = a0 + a1 + a2 + a3;
        float sq  = fmaf(a0, a0, fmaf(a1, a1, fmaf(a2, a2, a3 * a3)));
        if (k4) { stF<TY>(yws, base + 256, a4); sum += a4; sq = fmaf(a4, a4, sq); }
        sum += __shfl_xor(sum, 16); sq += __shfl_xor(sq, 16);
        sum += __shfl_xor(sum, 32); sq += __shfl_xor(sq, 32);
        if (tg == 0) { atomicAdd(&stat_s[o * 2], sum); atomicAdd(&stat_s[o * 2 + 1], sq); }
        base = (size_t)NB * 288 + (size_t)gs * 288 + l;
        stF<TY>(yws, base,       g0); stF<TY>(yws, base + 64,  g1);
        stF<TY>(yws, base + 128, g2); stF<TY>(yws, base + 192, g3);
        sum = g0 + g1 + g2 + g3;
        sq  = fmaf(g0, g0, fmaf(g1, g1, fmaf(g2, g2, g3 * g3)));
        if (k4) { stF<TY>(yws, base + 256, g4); sum += g4; sq = fmaf(g4, g4, sq); }
        sum += __shfl_xor(sum, 16); sq += __shfl_xor(sq, 16);
        sum += __shfl_xor(sum, 32); sq += __shfl_xor(sq, 32);
        if (tg == 0) { atomicAdd(&stat_s[32 + o * 2], sum); atomicAdd(&stat_s[32 + o * 2 + 1], sq); }
    }

    if (l < 63) {
        const int dd = l % 9, tc = l / 9;
        const u32* cw = wlU + C0W + dd * 8;
        const uint4 wca = *(const uint4*)(cw);
        const uint2 wcb = *(const uint2*)(cw + 4);
        const float cb  = bF[48 + dd];
        _Float16* eH = (_Float16*)eTH[s];
        const u32* eU = eTH[s];
        #pragma unroll 3
        for (int j = 0; j < 9; ++j) {
            int t = tc + 7 * j;
            if (t < 57) {
                const u32* r = eU + t * 8;
                uint4 ea = *(const uint4*)r;
                uint2 eb = *(const uint2*)(r + 4);
                float a = dot8(ea, wca, cb);
                a = DOT2(eb.x, wcb.x, a); a = DOT2(eb.y, wcb.y, a);
                eH[t * 16 + dd] = (_Float16)fmaxf(a, 0.f);
            }
        }
    }
    {
        _Float16* eH = (_Float16*)eTH[s];
        for (int m = l; m < 171; m += 64) { int t = m / 3, dd2 = 9 + m % 3; eH[t * 16 + dd2] = (_Float16)0.f; }
    }

    {
        const float b3v = bF[32 + o];
        float a0 = b3v, a1 = b3v, a2 = b3v, a3 = b3v, a4 = b3v;
        const u32* w3b = wlU + W3W + o * 44;
        const u32* eU  = eTH[s];
        #pragma unroll 2
        for (int kh = 0; kh < 5; ++kh) {
            const uint4 wa = *(const uint4*)(w3b + kh * 8);
            const uint2 wb = *(const uint2*)(w3b + kh * 8 + 4);
            const u32* r = eU + (3 * tg + kh) * 8;
            uint4 ea; uint2 eb;
            ea = *(const uint4*)(r);       eb = *(const uint2*)(r + 4);
            a0 = dot8(ea, wa, a0); a0 = DOT2(eb.x, wb.x, a0); a0 = DOT2(eb.y, wb.y, a0);
            ea = *(const uint4*)(r + 96);  eb = *(const uint2*)(r + 100);
            a1 = dot8(ea, wa, a1); a1 = DOT2(eb.x, wb.x, a1); a1 = DOT2(eb.y, wb.y, a1);
            ea = *(const uint4*)(r + 192); eb = *(const uint2*)(r + 196);
            a2 = dot8(ea, wa, a2); a2 = DOT2(eb.x, wb.x, a2); a2 = DOT2(eb.y, wb.y, a2);
            ea = *(const uint4*)(r + 288); eb = *(const uint2*)(r + 292);
            a3 = dot8(ea, wa, a3); a3 = DOT2(eb.x, wb.x, a3); a3 = DOT2(eb.y, wb.y, a3);
            if (k4) {
                ea = *(const uint4*)(r + 384); eb = *(const uint2*)(r + 388);
                a4 = dot8(ea, wa, a4); a4 = DOT2(eb.x, wb.x, a4); a4 = DOT2(eb.y, wb.y, a4);
            }
        }
        size_t base = (size_t)2 * NB * 288 + (size_t)gs * 288 + l;
        stF<TY>(yws, base,       a0); stF<TY>(yws, base + 64,  a1);
        stF<TY>(yws, base + 128, a2); stF<TY>(yws, base + 192, a3);
        float sum = a0 + a1 + a2 + a3;
        float sq  = fmaf(a0, a0, fmaf(a1, a1, fmaf(a2, a2, a3 * a3)));
        if (k4) { stF<TY>(yws, base + 256, a4); sum += a4; sq = fmaf(a4, a4, sq); }
        sum += __shfl_xor(sum, 16); sq += __shfl_xor(sq, 16);
        sum += __shfl_xor(sum, 32); sq += __shfl_xor(sq, 32);
        if (tg == 0) { atomicAdd(&stat_s[64 + o * 2], sum); atomicAdd(&stat_s[64 + o * 2 + 1], sq); }
    }
    __syncthreads();
    if (tid < 96) atomicAdd(&stat1[(blockIdx.x & (NSLOT - 1)) * 96 + tid], stat_s[tid]);
}

// ---------------- BN finalize (stage 1 or 2) ----------------
__global__ void kBN(const float* __restrict__ statp,
                    const float* __restrict__ g0, const float* __restrict__ be0,
                    const float* __restrict__ g1, const float* __restrict__ be1,
                    const float* __restrict__ g2, const float* __restrict__ be2,
                    float nInv, float* __restrict__ bnp)
{
    int tid = threadIdx.x;
    if (tid >= 48) return;
    int tau = tid / 16, o = tid % 16;
    float sum = 0.f, sq = 0.f;
    for (int sl = 0; sl < NSLOT; ++sl) {
        sum += statp[sl * 96 + tid * 2];
        sq  += statp[sl * 96 + tid * 2 + 1];
    }
    float mean = sum * nInv;
    float var  = sq * nInv - mean * mean;
    const float* g  = (tau == 0) ? g0 : (tau == 1) ? g1 : g2;
    const float* be = (tau == 0) ? be0 : (tau == 1) ? be1 : be2;
    float scale = g[o] / sqrtf(var + EPS);
    float shift = be[o] - mean * scale;
    bnp[tid * 2]     = scale;
    bnp[tid * 2 + 1] = shift;
}

// ---------------- Kernel C: BN1+relu, second convs (f16/dot2), BN2 stats ----------------
#define C_W1 0      // [16 o][6 kh][8dw], o-stride 52
#define C_W2 832    // [16 o][3 j ][8dw], o-stride 28
#define C_W3 1280   // [16 o][5 kh][8dw], o-stride 44
#define C_WL 1984

template<typename TY>
__global__ __launch_bounds__(512)
void kC(const TY* __restrict__ yws, const float* __restrict__ bn1,
        const float* __restrict__ t1w2, const float* __restrict__ t1b2,
        const float* __restrict__ t2w2, const float* __restrict__ t2b2,
        const float* __restrict__ c1w2, const float* __restrict__ c1b2,
        TY* __restrict__ zws, float* __restrict__ stat2)
{
    __shared__ __align__(16) u32 hT[3][8][144];   // f16 [18 t][8 dw] per tau,sample
    __shared__ __align__(16) u32 wl2[C_WL];
    __shared__ float bB[48];
    __shared__ float bnp[96];
    __shared__ float stat_s[96];

    const int tid = threadIdx.x;
    const int l   = tid & 63;
    const int s   = tid >> 6;
    const int gs  = blockIdx.x * 8 + s;

    if (tid < 96) { stat_s[tid] = 0.f; bnp[tid] = bn1[tid]; }
    {
        _Float16* hp = (_Float16*)wl2;
        for (int idx = tid; idx < 1536; idx += 512) { int o = idx / 96, r = idx % 96, kh = r >> 4, c = r & 15;
            hp[o * 104 + kh * 16 + c] = (_Float16)t1w2[o * 96 + c * 6 + kh]; }
        for (int idx = tid; idx < 768; idx += 512) { int o = idx / 48, r = idx % 48, j = r >> 4, c = r & 15;
            hp[2 * C_W2 + o * 56 + j * 16 + c] = (_Float16)t2w2[o * 48 + c * 3 + j]; }
        for (int idx = tid; idx < 1280; idx += 512) { int o = idx / 80, r = idx % 80, kh = r >> 4, c = r & 15;
            hp[2 * C_W3 + o * 88 + kh * 16 + c] = (_Float16)c1w2[o * 80 + c * 5 + kh]; }
        if (tid < 16) { bB[tid] = t1b2[tid]; bB[16 + tid] = t2b2[tid]; bB[32 + tid] = c1b2[tid]; }
    }
    __syncthreads();

    const int o = l & 15, tg = l >> 4;
    const bool k4 = (tg == 0);

    #pragma unroll
    for (int tau = 0; tau < 3; ++tau) {
        const float sc = bnp[(tau * 16 + o) * 2], sh = bnp[(tau * 16 + o) * 2 + 1];
        _Float16* hH = (_Float16*)hT[tau][s];
        const size_t yb = (size_t)tau * NB * 288 + (size_t)gs * 288 + l;
        #pragma unroll
        for (int k = 0; k < 4; ++k) {
            float v = ldF<TY>(yws, yb + k * 64);
            hH[(4 * k + tg) * 16 + o] = (_Float16)fmaxf(fmaf(v, sc, sh), 0.f);
        }
        if (l < 32) {
            float v = ldF<TY>(yws, yb + 256);
            hH[(16 + tg) * 16 + o] = (_Float16)fmaxf(fmaf(v, sc, sh), 0.f);
        }
    }

    {
        const float b = bB[o];
        float a0 = b, a1 = b;
        const u32* w = wl2 + C_W1 + o * 52;
        const u32* h0 = hT[0][s];
        #pragma unroll 2
        for (int kh = 0; kh < 6; ++kh) {
            const uint4 wa = *(const uint4*)(w + kh * 8);
            const uint4 wb = *(const uint4*)(w + kh * 8 + 4);
            const u32* r = h0 + (3 * tg + kh) * 8;
            uint4 ea = *(const uint4*)r, eb = *(const uint4*)(r + 4);
            a0 = dot8(eb, wb, dot8(ea, wa, a0));
            if (k4) {
                const u32* r2 = h0 + (12 + kh) * 8;
                uint4 fa = *(const uint4*)r2, fb = *(const uint4*)(r2 + 4);
                a1 = dot8(fb, wb, dot8(fa, wa, a1));
            }
        }
        size_t zb = (size_t)gs * 80;
        stF<TY>(zws, zb + o * 5 + tg, a0);
        float sum = a0, sq = a0 * a0;
        if (k4) { stF<TY>(zws, zb + o * 5 + 4, a1); sum += a1; sq = fmaf(a1, a1, sq); }
        sum += __shfl_xor(sum, 16); sq += __shfl_xor(sq, 16);
        sum += __shfl_xor(sum, 32); sq += __shfl_xor(sq, 32);
        if (tg == 0) { atomicAdd(&stat_s[o * 2], sum); atomicAdd(&stat_s[o * 2 + 1], sq); }
    }

    {
        const float b = bB[16 + o];
        float a0 = b, a1 = b;
        const u32* w = wl2 + C_W2 + o * 28;
        const u32* h1 = hT[1][s];
        #pragma unroll
        for (int j = 0; j < 3; ++j) {
            const uint4 wa = *(const uint4*)(w + j * 8);
            const uint4 wb = *(const uint4*)(w + j * 8 + 4);
            const u32* r = h1 + (3 * tg + 2 * j) * 8;
            uint4 ea = *(const uint4*)r, eb = *(const uint4*)(r + 4);
            a0 = dot8(eb, wb, dot8(ea, wa, a0));
            if (k4) {
                const u32* r2 = h1 + (12 + 2 * j) * 8;
                uint4 fa = *(const uint4*)r2, fb = *(const uint4*)(r2 + 4);
                a1 = dot8(fb, wb, dot8(fa, wa, a1));
            }
        }
        size_t zb = (size_t)NB * 80 + (size_t)gs * 80;
        stF<TY>(zws, zb + o * 5 + tg, a0);
        float sum = a0, sq = a0 * a0;
        if (k4) { stF<TY>(zws, zb + o * 5 + 4, a1); sum += a1; sq = fmaf(a1, a1, sq); }
        sum += __shfl_xor(sum, 16); sq += __shfl_xor(sq, 16);
        sum += __shfl_xor(sum, 32); sq += __shfl_xor(sq, 32);
        if (tg == 0) { atomicAdd(&stat_s[32 + o * 2], sum); atomicAdd(&stat_s[32 + o * 2 + 1], sq); }
    }

    {
        const float b = bB[32 + o];
        float a0 = b, a1 = b;
        const u32* w = wl2 + C_W3 + o * 44;
        const u32* h2 = hT[2][s];
        #pragma unroll 2
        for (int kh = 0; kh < 5; ++kh) {
            const uint4 wa = *(const uint4*)(w + kh * 8);
            const uint4 wb = *(const uint4*)(w + kh * 8 + 4);
            const u32* r = h2 + (3 * tg + kh) * 8;
            uint4 ea = *(const uint4*)r, eb = *(const uint4*)(r + 4);
            a0 = dot8(eb, wb, dot8(ea, wa, a0));
            if (k4) {
                const u32* r2 = h2 + (12 + kh) * 8;
                uint4 fa = *(const uint4*)r2, fb = *(const uint4*)(r2 + 4);
                a1 = dot8(fb, wb, dot8(fa, wa, a1));
            }
        }
        size_t zb = (size_t)2 * NB * 80 + (size_t)gs * 80;
        stF<TY>(zws, zb + o * 5 + tg, a0);
        float sum = a0, sq = a0 * a0;
        if (k4) { stF<TY>(zws, zb + o * 5 + 4, a1); sum += a1; sq = fmaf(a1, a1, sq); }
        sum += __shfl_xor(sum, 16); sq += __shfl_xor(sq, 16);
        sum += __shfl_xor(sum, 32); sq += __shfl_xor(sq, 32);
        if (tg == 0) { atomicAdd(&stat_s[64 + o * 2], sum); atomicAdd(&stat_s[64 + o * 2 + 1], sq); }
    }
    __syncthreads();
    if (tid < 96) atomicAdd(&stat2[(blockIdx.x & (NSLOT - 1)) * 96 + tid], stat_s[tid]);
}

// ---------------- Kernel E: BN2+relu, feats, FC (f16 dot2), tanh ----------------
// 16 samples / 512 threads: halves the 32 KB fcw staging per sample.
template<typename TY>
__global__ __launch_bounds__(512)
void kE(const TY* __restrict__ zws, const float* __restrict__ bn2,
        const float* __restrict__ fcw, const float* __restrict__ fcb,
        float* __restrict__ out)
{
    __shared__ __align__(16) u32 fcwH[8000];
    __shared__ __align__(16) u32 featsH[16][160];
    __shared__ float fcb_s[50];
    __shared__ float bnp[96];
    const int tid = threadIdx.x;
    const int s0  = blockIdx.x * 16;

    if (tid < 96) bnp[tid] = bn2[tid];
    if (tid < 50) fcb_s[tid] = fcb[tid];
    for (int idx = tid; idx < 8000; idx += 512) {
        int fp = idx / 50, u = idx % 50;
        union { u32 v; _Float16 h[2]; } pk;
        pk.h[0] = (_Float16)fcw[(2 * fp) * 50 + u];
        pk.h[1] = (_Float16)fcw[(2 * fp + 1) * 50 + u];
        fcwH[idx] = pk.v;
    }
    __syncthreads();

    for (int idx = tid; idx < 5120; idx += 512) {
        int s = idx / 320, f = idx % 320;
        int g = f / 80; int tau = (g == 3) ? 2 : g;
        int r = f % 80, o = r / 5;
        float v = ldF<TY>(zws, (size_t)tau * NB * 80 + (size_t)(s0 + s) * 80 + r);
        float x = fmaxf(fmaf(v, bnp[(tau * 16 + o) * 2], bnp[(tau * 16 + o) * 2 + 1]), 0.f);
        ((_Float16*)featsH[s])[f] = (_Float16)x;
    }
    __syncthreads();

    // 16*50 = 800 outputs: tid (<512) and tid+512 (<800 -> tid<288)
    const int sA = tid / 50, uA = tid % 50;
    const int iB = tid + 512, sB = iB / 50, uB = iB % 50;
    const bool hasB = (tid < 288);
    float accA = fcb_s[uA];
    float accB = hasB ? fcb_s[uB] : 0.f;
    #pragma unroll 4
    for (int fp = 0; fp < 160; ++fp) {
        u32 w1 = fcwH[fp * 50 + uA];
        accA = DOT2(featsH[sA][fp], w1, accA);
        if (hasB) {
            u32 w2 = fcwH[fp * 50 + uB];
            accB = DOT2(featsH[sB][fp], w2, accB);
        }
    }
    out[(size_t)(s0 + sA) * 50 + uA] = tanhf(accA);
    if (hasB) out[(size_t)(s0 + sB) * 50 + uB] = tanhf(accB);
}

// ---------------- host launcher ----------------
template<typename TY>
static void launch_all(void* const* d_in, void* d_out, void* d_ws, hipStream_t stream)
{
    const float* raw  = (const float*)d_in[0];
    const float* eegf = (const float*)d_in[1];
    const float* fgw1 = (const float*)d_in[2];
    const float* fgb1 = (const float*)d_in[3];
    const float* fgw2 = (const float*)d_in[4];
    const float* fgb2 = (const float*)d_in[5];
    const float* t1w1 = (const float*)d_in[6];
    const float* t1b1 = (const float*)d_in[7];
    const float* t1g1 = (const float*)d_in[8];
    const float* t1be1= (const float*)d_in[9];
    const float* t1w2 = (const float*)d_in[10];
    const float* t1b2 = (const float*)d_in[11];
    const float* t1g2 = (const float*)d_in[12];
    const float* t1be2= (const float*)d_in[13];
    const float* t2w1 = (const float*)d_in[14];
    const float* t2b1 = (const float*)d_in[15];
    const float* t2g1 = (const float*)d_in[16];
    const float* t2be1= (const float*)d_in[17];
    const float* t2w2 = (const float*)d_in[18];
    const float* t2b2 = (const float*)d_in[19];
    const float* t2g2 = (const float*)d_in[20];
    const float* t2be2= (const float*)d_in[21];
    const float* c0w  = (const float*)d_in[22];
    const float* c0b  = (const float*)d_in[23];
    const float* c1w1 = (const float*)d_in[24];
    const float* c1b1 = (const float*)d_in[25];
    const float* c1g1 = (const float*)d_in[26];
    const float* c1be1= (const float*)d_in[27];
    const float* c1w2 = (const float*)d_in[28];
    const float* c1b2 = (const float*)d_in[29];
    const float* c1g2 = (const float*)d_in[30];
    const float* c1be2= (const float*)d_in[31];
    const float* fcw  = (const float*)d_in[32];
    const float* fcb  = (const float*)d_in[33];

    char* ws = (char*)d_ws;
    TY* yws = (TY*)ws;
    TY* zws = (TY*)(ws + (size_t)3 * NB * 288 * sizeof(TY));
    float* stat1 = (float*)(ws + (size_t)3 * NB * 288 * sizeof(TY) + (size_t)3 * NB * 80 * sizeof(TY));
    float* stat2 = stat1 + NSLOT * 96;
    float* bn1   = stat2 + NSLOT * 96;
    float* bn2   = bn1 + 96;

    hipMemsetAsync(stat1, 0, 2 * NSLOT * 96 * sizeof(float), stream);

    kA<TY><<<NB / 8, 512, 0, stream>>>(raw, eegf, fgw1, fgb1, fgw2, fgb2,
                                       t1w1, t1b1, t2w1, t2b1, c0w, c0b, c1w1, c1b1,
                                       yws, stat1);
    kBN<<<1, 64, 0, stream>>>(stat1, t1g1, t1be1, t2g1, t2be1, c1g1, c1be1,
                              1.f / (float)((size_t)NB * 18), bn1);
    kC<TY><<<NB / 8, 512, 0, stream>>>(yws, bn1, t1w2, t1b2, t2w2, t2b2, c1w2, c1b2,
                                       zws, stat2);
    kBN<<<1, 64, 0, stream>>>(stat2, t1g2, t1be2, t2g2, t2be2, c1g2, c1be2,
                              1.f / (float)((size_t)NB * 5), bn2);
    kE<TY><<<NB / 16, 512, 0, stream>>>(zws, bn2, fcw, fcb, (float*)d_out);
}

extern "C" void kernel_launch(void* const* d_in, const int* in_sizes, int n_in,
                              void* d_out, int out_size, void* d_ws, size_t ws_size,
                              hipStream_t stream)
{
    (void)in_sizes; (void)n_in; (void)out_size;
    size_t statBytes = (2 * NSLOT * 96 + 192) * sizeof(float);
    size_t needF32 = ((size_t)3 * NB * 288 + (size_t)3 * NB * 80) * 4 + statBytes;
    if (ws_size >= needF32)
        launch_all<float>(d_in, d_out, d_ws, stream);
    else
        launch_all<bf16>(d_in, d_out, d_ws, stream);
}